// Round 1
// baseline (196.102 us; speedup 1.0000x reference)
//
#include <hip/hip_runtime.h>
#include <hip/hip_bf16.h>
#include <math.h>

#define NB   4
#define CIN  128
#define HH   96
#define WW   96
#define HWN  (HH*WW)        // 9216
#define NHW  (NB*HWN)       // 36864
#define COUT 128
#define KW   9
#define KDIM (CIN*KW)       // 1152
#define GSZ  16
#define PXB  32             // pixels per dcn block
#define NBLK (NHW/PXB)      // 1152

typedef __attribute__((ext_vector_type(8))) short bf16x8;   // 8 bf16 (4 VGPRs)
typedef __attribute__((ext_vector_type(4))) float f32x4;    // 4 fp32 acc

// ws layout (float units)
#define OFF_WAH   0          // 73728 floats = 147456 ushorts: W hi, A-frag identity order
#define OFF_DX    147456
#define OFF_DY    184320
#define OFF_MASK  221184
#define OFF_GN    258048     // 128: s1[64], s2[64]
#define OFF_MAP   258240     // 256 ints: D-layout map[lane*4+reg] = (m<<4)|n
#define OFF_PAIR  258496     // 32 ints: B-slot j holds channel pairB[j]

#define HEADB 1152           // head blocks in pre_kernel (8 slots x 32 cgs each)

__device__ __forceinline__ ushort f2bf(float f) {
    union { float f; uint u; } v; v.f = f;
    uint r = v.u + 0x7fffu + ((v.u >> 16) & 1u);   // RNE to bf16
    return (ushort)(r >> 16);
}
__device__ __forceinline__ float bf2f(ushort h) {
    union { uint u; float f; } v; v.u = ((uint)h) << 16;
    return v.f;
}

// Workgroup barrier that drains LDS ops but leaves global loads in flight
// (r9/r11-proven correct).
__device__ __forceinline__ void barrier_keep_vm() {
    asm volatile("s_waitcnt lgkmcnt(0)\n\ts_barrier" ::: "memory");
}

// ------------------------------------------------- pre: head (b<HEADB) + wsplit/probes (b>=HEADB)
// Head v2: sliding-window conv. Each thread: 4 consecutive pixels x 4 channels.
// Per channel: 3 rows x (1 float4 + 2 halo scalars) = 9 load instrs, 108 FMAs.
// 12:1 FMA:load issue ratio; 1152 heavy blocks (was 576).
__global__ __launch_bounds__(256) void pre_kernel(const float* __restrict__ x,
                                                  const float* __restrict__ w_head,
                                                  const float* __restrict__ b_head,
                                                  const float* __restrict__ wd,
                                                  ushort* __restrict__ wah,
                                                  float* __restrict__ dxv,
                                                  float* __restrict__ dyv,
                                                  float* __restrict__ maskv,
                                                  float* __restrict__ gn_part,
                                                  int* __restrict__ map,
                                                  int* __restrict__ pairB) {
    __shared__ float wl[CIN * 28];      // 14.3 KB: wl[c*28 + kk*3 + j], 16B-aligned rows
    __shared__ float sp[32][8][13];     // 13.3 KB: [cg][slot][q*3+j], +1 pad -> <=2-way bank alias
    const int b = blockIdx.x, t = threadIdx.x;

    if (b >= HEADB) {
        // ---------------- prep part (r8-proven indexing), hi only
        const int bb = b - HEADB;
        int i = bb * 256 + t;                     // < 147456
        {
            int e  = i & 7;
            int l  = (i >> 3) & 63;
            int ot = (i >> 9) & 7;
            int q  = (i >> 12) & 3;
            int k  = i >> 14;                     // 0..8
            int o  = ot * 16 + (l & 15);
            int c  = q * 32 + (l >> 4) * 8 + e;
            wah[i] = f2bf(wd[o * KDIM + c * KW + k]);
        }
        if (bb == 0 && t < 128) gn_part[t] = 0.f;
        if (bb == 0 && t < 64) {
            // D-layout probe (HW-verified r4/r6)
            int l = t;
            bf16x8 A1 = {}, B1 = {}, A2 = {}, B2 = {};
            if ((l >> 4) == 0) {
                A1[0] = (short)f2bf((float)((l & 15) + 1));
                B1[0] = (short)f2bf(1.0f);
                A2[0] = (short)f2bf(1.0f);
                B2[0] = (short)f2bf((float)((l & 15) + 1));
            }
            f32x4 d1 = {0.f,0.f,0.f,0.f}, d2 = {0.f,0.f,0.f,0.f};
            d1 = __builtin_amdgcn_mfma_f32_16x16x32_bf16(A1, B1, d1, 0, 0, 0);
            d2 = __builtin_amdgcn_mfma_f32_16x16x32_bf16(A2, B2, d2, 0, 0, 0);
#pragma unroll
            for (int r = 0; r < 4; ++r) {
                int m = (int)(d1[r] + 0.5f) - 1;
                int n = (int)(d2[r] + 0.5f) - 1;
                map[l * 4 + r] = (m << 4) | n;
            }
        }
        if (bb == 1 && t < 64) {
            // A/B k-slot pairing probe (HW-verified r6): pairB[j] = s
            int l = t;
            union { bf16x8 v; short a[8]; } B;
#pragma unroll
            for (int e = 0; e < 8; ++e) {
                float val = (float)(1u << (((l >> 4) * 8 + e) & 31));
                B.a[e] = (short)f2bf(val);
            }
#pragma unroll
            for (int s = 0; s < 32; ++s) {
                union { bf16x8 v; short a[8]; } A;
#pragma unroll
                for (int e = 0; e < 8; ++e) A.a[e] = 0;
                if ((l >> 4) == (s >> 3)) A.a[s & 7] = (short)f2bf(1.0f);
                f32x4 d = {0.f, 0.f, 0.f, 0.f};
                d = __builtin_amdgcn_mfma_f32_16x16x32_bf16(A.v, B.v, d, 0, 0, 0);
                float v0 = d[0];
                if (l == 0 && v0 > 0.f) {
                    int ex; frexpf(v0, &ex);     // v0 = 2^j -> ex = j+1
                    int j = ex - 1;
                    if (j >= 0 && j < 32) pairB[j] = s;
                }
            }
        }
        return;
    }

    // ---------------- head v2
    // stage weights: w_head linear (j,c,kk) = j*1152 + c*9 + kk  ->  wl[c*28 + kk*3 + j]
    for (int i = t; i < 3456; i += 256) {
        int j = i / KDIM, r = i - j * KDIM;
        int c = r / 9, kk = r - c * 9;
        wl[c * 28 + kk * 3 + j] = w_head[i];
    }
    __syncthreads();

    const int sl = t & 7;               // slot in block (4 px each)
    const int cg = t >> 3;              // 0..31, 4 channels each
    const int p0 = b * 32 + sl * 4;     // first pixel of slot; 96%4==0 -> slot stays in one row
    const int n  = p0 / HWN;
    const int hw = p0 - n * HWN;
    const int h  = hw / WW;
    const int w0 = hw - h * WW;         // multiple of 4 -> float4-aligned
    const float* xn = x + (size_t)n * CIN * HWN;
    const bool lok = (w0 > 0);
    const bool rok = (w0 < WW - 4);

    float acc[12];
#pragma unroll
    for (int i = 0; i < 12; ++i) acc[i] = 0.f;

#pragma unroll
    for (int cc = 0; cc < 4; ++cc) {
        const int c = cg * 4 + cc;
        const float* xc = xn + (size_t)c * HWN;
        // load 3 rows x 6 cols window: v[r][i] = x[y, w0+i-1] (0 if OOB)
        float v[3][6];
#pragma unroll
        for (int r = 0; r < 3; ++r) {
            int y = h - 1 + r;
            if (y >= 0 && y < HH) {
                const float* xr = xc + y * WW + w0;
                float4 m4 = *(const float4*)xr;
                v[r][1] = m4.x; v[r][2] = m4.y; v[r][3] = m4.z; v[r][4] = m4.w;
                v[r][0] = lok ? xr[-1] : 0.f;
                v[r][5] = rok ? xr[4]  : 0.f;
            } else {
#pragma unroll
                for (int i = 0; i < 6; ++i) v[r][i] = 0.f;
            }
        }
        // weights for this channel: 7x ds_read_b128 (28 floats, last is pad)
        float wr[28];
        const float* wc = &wl[c * 28];
#pragma unroll
        for (int i2 = 0; i2 < 7; ++i2) {
            float4 q4 = *(const float4*)(wc + i2 * 4);
            wr[i2 * 4 + 0] = q4.x; wr[i2 * 4 + 1] = q4.y;
            wr[i2 * 4 + 2] = q4.z; wr[i2 * 4 + 3] = q4.w;
        }
#pragma unroll
        for (int ky = 0; ky < 3; ++ky)
#pragma unroll
            for (int kx = 0; kx < 3; ++kx) {
                const int kk = ky * 3 + kx;
                const float wj0 = wr[kk * 3 + 0];
                const float wj1 = wr[kk * 3 + 1];
                const float wj2 = wr[kk * 3 + 2];
#pragma unroll
                for (int q = 0; q < 4; ++q) {
                    float val = v[ky][q + kx];
                    acc[q * 3 + 0] = fmaf(val, wj0, acc[q * 3 + 0]);
                    acc[q * 3 + 1] = fmaf(val, wj1, acc[q * 3 + 1]);
                    acc[q * 3 + 2] = fmaf(val, wj2, acc[q * 3 + 2]);
                }
            }
    }
#pragma unroll
    for (int i = 0; i < 12; ++i) sp[cg][sl][i] = acc[i];
    __syncthreads();
    // fold 32 cgs -> 8 (wave 0 only)
    if (cg < 8) {
#pragma unroll
        for (int k = 8; k < 32; k += 8)
#pragma unroll
            for (int i = 0; i < 12; ++i) sp[cg][sl][i] += sp[cg + k][sl][i];
    }
    __syncthreads();
    if (t < 32) {
        const int s2 = t >> 2, q = t & 3;
        float b0 = b_head[0], b1 = b_head[1], b2 = b_head[2];
#pragma unroll
        for (int cgi = 0; cgi < 8; ++cgi) {
            b0 += sp[cgi][s2][q * 3 + 0];
            b1 += sp[cgi][s2][q * 3 + 1];
            b2 += sp[cgi][s2][q * 3 + 2];
        }
        int pp = b * 32 + t;
        dxv[pp]   = 0.25f * tanhf(b0);
        dyv[pp]   = 0.25f * tanhf(b1);
        maskv[pp] = 1.f / (1.f + expf(-b2));
    }
}

// ---------------------------------------------------------------- main DCN
// r11's pipeline skeleton (PASSED), plain-bf16 (no lo path): 4 MFMAs/chunk,
// half the LDS, ~48 live regs across the barrier -> fits 60-VGPR budget, no spill.
__global__ __launch_bounds__(256) void dcn_kernel(const float* __restrict__ x,
                                                  const ushort* __restrict__ wah,
                                                  const float* __restrict__ dxv,
                                                  const float* __restrict__ dyv,
                                                  const float* __restrict__ maskv,
                                                  const int* __restrict__ map,
                                                  const int* __restrict__ pairB,
                                                  float* __restrict__ out,
                                                  float* __restrict__ gn_part) {
    __shared__ __attribute__((aligned(16))) ushort sBh[2][4 * PXB * 8];  // 4 KB
    __shared__ float sMask[PXB];
    __shared__ float gred[16];

    const int t = threadIdx.x;
    const int lane = t & 63;
    const int wv = t >> 6;
    const int lg = lane >> 4;
    const int ml = lane & 15;
    const int pix = t & 31;
    const int sg  = t >> 5;         // 0..7: slot quad sg*4..sg*4+3

    int b = blockIdx.x;
    int nb = (b & 7) * (NBLK / 8) + (b >> 3);     // XCD swizzle
    const int p0  = nb * PXB;
    const int n   = p0 / HWN;
    const int hw0 = p0 % HWN;
    const float* xn = x + (size_t)n * CIN * HWN;

    if (t < PXB) sMask[t] = maskv[p0 + t];
    if (t < 16) gred[t] = 0.f;

    const float dxl = dxv[p0 + pix];
    const float dyl = dyv[p0 + pix];
    const int hme = (hw0 + pix) / WW;
    const int wme = (hw0 + pix) % WW;

    int chn[4];
#pragma unroll
    for (int e = 0; e < 4; ++e) chn[e] = pairB[sg * 4 + e] & 31;

    f32x4 acc[2][2];
#pragma unroll
    for (int i = 0; i < 2; i++)
#pragma unroll
        for (int j = 0; j < 2; j++) acc[i][j] = (f32x4){0.f, 0.f, 0.f, 0.f};

    const int oyc[9] = {0, 0, 0, 1, 0, -1, 1, 1, -1};
    const int oxc[9] = {0, 1, -1, 0, 0, 0, 1, -1, 1};
    const int ncl[9] = {1, 2, 2, 2, 1, 2, 4, 4, 4};

    int aa[4]; float wq[4];
    float raw[4][4];                 // [channel e][corner] — prefetched gathers
    bf16x8 An0, An1;                 // prefetched A frags (hi only)

    // ---- prologue: corners tap0, issue chunk(0,0) gathers + A frags
    {
        float py = (float)(hme - 1), px = (float)(wme - 1);
        float fy0 = floorf(py), fx0 = floorf(px);
        int y0 = (int)fy0, x0 = (int)fx0;
        float fy = py - fy0, fx = px - fx0;
#pragma unroll
        for (int j = 0; j < 4; ++j) {
            int yy = y0 + (j >> 1), xx = x0 + (j & 1);
            float wb = ((j >> 1) ? fy : 1.f - fy) * ((j & 1) ? fx : 1.f - fx);
            bool ok = (yy >= 0) && (yy < HH) && (xx >= 0) && (xx < WW);
            aa[j] = min(max(yy, 0), HH - 1) * WW + min(max(xx, 0), WW - 1);
            wq[j] = ok ? wb : 0.f;
        }
#pragma unroll
        for (int e = 0; e < 4; ++e) raw[e][0] = xn[(size_t)chn[e] * HWN + aa[0]];
        const size_t abase = (size_t)(wv * 2) * 512 + lane * 8;
        An0 = *(const bf16x8*)(wah + abase);
        An1 = *(const bf16x8*)(wah + abase + 512);
    }

#pragma unroll
    for (int j = 0; j < 36; ++j) {
        const int k = j >> 2;
        const int NC = ncl[k];
        // current A frags
        bf16x8 Ah0 = An0, Ah1 = An1;
        // ---- pack set j (waits on j's gathers — issued one iteration ago)
        union { short4 v; ushort u[4]; } hv;
#pragma unroll
        for (int e = 0; e < 4; ++e) {
            float s = raw[e][0] * wq[0];
            if (NC >= 2) s += raw[e][1] * wq[1];
            if (NC == 4) s += raw[e][2] * wq[2] + raw[e][3] * wq[3];
            hv.u[e] = f2bf(s);
        }
        const int wbase = ((sg >> 1) * PXB + pix) * 8 + (sg & 1) * 4;
        *(short4*)&sBh[j & 1][wbase] = hv.v;
        // ---- prefetch set j+1 (global loads stay in flight across the barrier)
        if (j < 35) {
            const int jn = j + 1, kn = jn >> 2, qn = jn & 3;
            if (qn == 0) {
                const int ky = kn / 3, kx = kn - ky * 3;
                float py = (float)(hme - 1 + ky) + (float)oyc[kn] * dxl;
                float px = (float)(wme - 1 + kx) + (float)oxc[kn] * dyl;
                float fy0 = floorf(py), fx0 = floorf(px);
                int y0 = (int)fy0, x0 = (int)fx0;
                float fy = py - fy0, fx = px - fx0;
#pragma unroll
                for (int jj = 0; jj < 4; ++jj) {
                    int yy = y0 + (jj >> 1), xx = x0 + (jj & 1);
                    float wb = ((jj >> 1) ? fy : 1.f - fy) * ((jj & 1) ? fx : 1.f - fx);
                    bool ok = (yy >= 0) && (yy < HH) && (xx >= 0) && (xx < WW);
                    aa[jj] = min(max(yy, 0), HH - 1) * WW + min(max(xx, 0), WW - 1);
                    wq[jj] = ok ? wb : 0.f;
                }
                if (ncl[kn] == 2 && oxc[kn] == 0) { aa[1] = aa[2]; wq[1] = wq[2]; }
            }
            const int NCn = ncl[kn];
            const int ccn = qn * 32;
#pragma unroll
            for (int e = 0; e < 4; ++e) {
                const float* xc = xn + (size_t)(ccn + chn[e]) * HWN;
                raw[e][0] = xc[aa[0]];
                if (NCn >= 2) raw[e][1] = xc[aa[1]];
                if (NCn == 4) { raw[e][2] = xc[aa[2]]; raw[e][3] = xc[aa[3]]; }
            }
            const size_t abase = (size_t)((kn * 4 + qn) * 8 + wv * 2) * 512 + lane * 8;
            An0 = *(const bf16x8*)(wah + abase);
            An1 = *(const bf16x8*)(wah + abase + 512);
        }
        barrier_keep_vm();   // drains LDS writes; gathers stay outstanding
        // ---- MFMAs on buf[j&1]
#pragma unroll
        for (int pt = 0; pt < 2; ++pt) {
            const int rbase = (lg * PXB + pt * 16 + ml) * 8;
            bf16x8 Bh = *(const bf16x8*)&sBh[j & 1][rbase];
            acc[0][pt] = __builtin_amdgcn_mfma_f32_16x16x32_bf16(Ah0, Bh, acc[0][pt], 0, 0, 0);
            acc[1][pt] = __builtin_amdgcn_mfma_f32_16x16x32_bf16(Ah1, Bh, acc[1][pt], 0, 0, 0);
        }
    }

    // ---- epilogue: mask, scatter via probed D layout, GN partials (r8-proven)
    int4 mn4 = *(const int4*)&map[lane * 4];
    int mn[4] = {mn4.x, mn4.y, mn4.z, mn4.w};
    float s1g[2] = {0.f, 0.f}, s2g[2] = {0.f, 0.f};
#pragma unroll
    for (int ot = 0; ot < 2; ++ot) {
        int otile = wv * 32 + ot * 16;
#pragma unroll
        for (int pt = 0; pt < 2; ++pt) {
#pragma unroll
            for (int r = 0; r < 4; ++r) {
                int m = mn[r] >> 4, nn2 = mn[r] & 15;
                int p = pt * 16 + nn2;
                float v = acc[ot][pt][r] * sMask[p];
                s1g[ot] += v;
                s2g[ot] += v * v;
                out[((size_t)n * COUT + otile + m) * HWN + hw0 + p] = v;
            }
        }
    }
#pragma unroll
    for (int ot = 0; ot < 2; ++ot) {
        int g = wv * 2 + ot;
        atomicAdd(&gred[g * 2 + 0], s1g[ot]);
        atomicAdd(&gred[g * 2 + 1], s2g[ot]);
    }
    __syncthreads();
    if (t < 8) {
        atomicAdd(&gn_part[n * 8 + t],      gred[t * 2 + 0]);
        atomicAdd(&gn_part[64 + n * 8 + t], gred[t * 2 + 1]);
    }
}

// ---------------------------------------------------------------- GN apply (stats inline)
__global__ __launch_bounds__(256) void gn_apply(float* __restrict__ out,
                                                const float* __restrict__ gn_part,
                                                const float* __restrict__ gamma,
                                                const float* __restrict__ beta) {
    int i4 = blockIdx.x * 256 + threadIdx.x;
    size_t e = (size_t)i4 * 4;
    int og = (int)(e / HWN);
    int n = og >> 7, o = og & 127;
    int s = n * 8 + (o >> 4);
    const float cnt = (float)GSZ * (float)HWN;
    float s1 = gn_part[s], s2 = gn_part[64 + s];
    float mu = s1 / cnt;
    float var = s2 / cnt - mu * mu;
    float inv = rsqrtf(var + 1e-5f);
    float ga = gamma[o] * inv;
    float be = beta[o] - mu * ga;
    float4 v = *(float4*)(out + e);
    v.x = fmaxf(fmaf(v.x, ga, be), 0.f);
    v.y = fmaxf(fmaf(v.y, ga, be), 0.f);
    v.z = fmaxf(fmaf(v.z, ga, be), 0.f);
    v.w = fmaxf(fmaf(v.w, ga, be), 0.f);
    *(float4*)(out + e) = v;
}

// ---------------------------------------------------------------- launch
extern "C" void kernel_launch(void* const* d_in, const int* in_sizes, int n_in,
                              void* d_out, int out_size, void* d_ws, size_t ws_size,
                              hipStream_t stream) {
    const float* x       = (const float*)d_in[0];
    const float* w_head  = (const float*)d_in[1];
    const float* b_head  = (const float*)d_in[2];
    const float* w_dcn   = (const float*)d_in[3];
    const float* gamma   = (const float*)d_in[4];
    const float* beta    = (const float*)d_in[5];
    float* out = (float*)d_out;
    float* ws  = (float*)d_ws;

    ushort* wah    = (ushort*)(ws + OFF_WAH);
    float* dxv     = ws + OFF_DX;
    float* dyv     = ws + OFF_DY;
    float* maskv   = ws + OFF_MASK;
    float* gn_part = ws + OFF_GN;
    int*   map     = (int*)(ws + OFF_MAP);
    int*   pairB   = (int*)(ws + OFF_PAIR);

    pre_kernel<<<HEADB + 576, 256, 0, stream>>>(x, w_head, b_head, w_dcn, wah,
                                                dxv, dyv, maskv, gn_part, map, pairB);
    dcn_kernel<<<NBLK, 256, 0, stream>>>(x, wah, dxv, dyv, maskv, map, pairB, out, gn_part);
    gn_apply<<<(NB * COUT * HWN) / 4 / 256, 256, 0, stream>>>(out, gn_part, gamma, beta);
}

// Round 2
// 194.325 us; speedup vs baseline: 1.0091x; 1.0091x over previous
//
#include <hip/hip_runtime.h>
#include <hip/hip_bf16.h>
#include <math.h>

#define NB   4
#define CIN  128
#define HH   96
#define WW   96
#define HWN  (HH*WW)        // 9216
#define NHW  (NB*HWN)       // 36864
#define COUT 128
#define KW   9
#define KDIM (CIN*KW)       // 1152
#define GSZ  16
#define PXB  32             // pixels per dcn block
#define NBLK (NHW/PXB)      // 1152
#define XPB  64             // pixels per xpose block

typedef __attribute__((ext_vector_type(8))) short bf16x8;   // 8 bf16 (4 VGPRs)
typedef __attribute__((ext_vector_type(4))) float f32x4;    // 4 fp32 acc

// ws layout (float units)
#define OFF_WAH   0          // 73728 floats = 147456 ushorts: W hi, A-frag identity order
#define OFF_DX    147456
#define OFF_DY    184320
#define OFF_MASK  221184
#define OFF_GN    258048     // 128: s1[64], s2[64]
#define OFF_MAP   258240     // 256 ints: D-layout map[lane*4+reg] = (m<<4)|n
#define OFF_PAIR  258496     // 32 ints: B-slot j holds channel pairB[j]
#define OFF_XT    258560     // 4718592 floats: xt[n][hw][slot-permuted c] (19 MB)

#define HEADB 1152           // head blocks in pre_kernel (8 slots x 32 cgs each)

__device__ __forceinline__ ushort f2bf(float f) {
    union { float f; uint u; } v; v.f = f;
    uint r = v.u + 0x7fffu + ((v.u >> 16) & 1u);   // RNE to bf16
    return (ushort)(r >> 16);
}

// Workgroup barrier that drains LDS ops but leaves global loads in flight
// (r9/r11-proven correct).
__device__ __forceinline__ void barrier_keep_vm() {
    asm volatile("s_waitcnt lgkmcnt(0)\n\ts_barrier" ::: "memory");
}

// ------------------------------------------------- pre: head (b<HEADB) + wsplit/probes (b>=HEADB)
__global__ __launch_bounds__(256) void pre_kernel(const float* __restrict__ x,
                                                  const float* __restrict__ w_head,
                                                  const float* __restrict__ b_head,
                                                  const float* __restrict__ wd,
                                                  ushort* __restrict__ wah,
                                                  float* __restrict__ dxv,
                                                  float* __restrict__ dyv,
                                                  float* __restrict__ maskv,
                                                  float* __restrict__ gn_part,
                                                  int* __restrict__ map,
                                                  int* __restrict__ pairB) {
    __shared__ float wl[CIN * 28];      // 14.3 KB: wl[c*28 + kk*3 + j], 16B-aligned rows
    __shared__ float sp[32][8][13];     // 13.3 KB: [cg][slot][q*3+j]
    const int b = blockIdx.x, t = threadIdx.x;

    if (b >= HEADB) {
        // ---------------- prep part (r8-proven indexing), hi only
        const int bb = b - HEADB;
        int i = bb * 256 + t;                     // < 147456
        {
            int e  = i & 7;
            int l  = (i >> 3) & 63;
            int ot = (i >> 9) & 7;
            int q  = (i >> 12) & 3;
            int k  = i >> 14;                     // 0..8
            int o  = ot * 16 + (l & 15);
            int c  = q * 32 + (l >> 4) * 8 + e;
            wah[i] = f2bf(wd[o * KDIM + c * KW + k]);
        }
        if (bb == 0 && t < 128) gn_part[t] = 0.f;
        if (bb == 0 && t < 64) {
            // D-layout probe (HW-verified r4/r6)
            int l = t;
            bf16x8 A1 = {}, B1 = {}, A2 = {}, B2 = {};
            if ((l >> 4) == 0) {
                A1[0] = (short)f2bf((float)((l & 15) + 1));
                B1[0] = (short)f2bf(1.0f);
                A2[0] = (short)f2bf(1.0f);
                B2[0] = (short)f2bf((float)((l & 15) + 1));
            }
            f32x4 d1 = {0.f,0.f,0.f,0.f}, d2 = {0.f,0.f,0.f,0.f};
            d1 = __builtin_amdgcn_mfma_f32_16x16x32_bf16(A1, B1, d1, 0, 0, 0);
            d2 = __builtin_amdgcn_mfma_f32_16x16x32_bf16(A2, B2, d2, 0, 0, 0);
#pragma unroll
            for (int r = 0; r < 4; ++r) {
                int m = (int)(d1[r] + 0.5f) - 1;
                int n = (int)(d2[r] + 0.5f) - 1;
                map[l * 4 + r] = (m << 4) | n;
            }
        }
        if (bb == 1 && t < 64) {
            // A/B k-slot pairing probe (HW-verified r6): pairB[j] = s
            int l = t;
            union { bf16x8 v; short a[8]; } B;
#pragma unroll
            for (int e = 0; e < 8; ++e) {
                float val = (float)(1u << (((l >> 4) * 8 + e) & 31));
                B.a[e] = (short)f2bf(val);
            }
#pragma unroll
            for (int s = 0; s < 32; ++s) {
                union { bf16x8 v; short a[8]; } A;
#pragma unroll
                for (int e = 0; e < 8; ++e) A.a[e] = 0;
                if ((l >> 4) == (s >> 3)) A.a[s & 7] = (short)f2bf(1.0f);
                f32x4 d = {0.f, 0.f, 0.f, 0.f};
                d = __builtin_amdgcn_mfma_f32_16x16x32_bf16(A.v, B.v, d, 0, 0, 0);
                float v0 = d[0];
                if (l == 0 && v0 > 0.f) {
                    int ex; frexpf(v0, &ex);     // v0 = 2^j -> ex = j+1
                    int j = ex - 1;
                    if (j >= 0 && j < 32) pairB[j] = s;
                }
            }
        }
        return;
    }

    // ---------------- head v2 (sliding-window conv)
    for (int i = t; i < 3456; i += 256) {
        int j = i / KDIM, r = i - j * KDIM;
        int c = r / 9, kk = r - c * 9;
        wl[c * 28 + kk * 3 + j] = w_head[i];
    }
    __syncthreads();

    const int sl = t & 7;               // slot in block (4 px each)
    const int cg = t >> 3;              // 0..31, 4 channels each
    const int p0 = b * 32 + sl * 4;     // first pixel of slot
    const int n  = p0 / HWN;
    const int hw = p0 - n * HWN;
    const int h  = hw / WW;
    const int w0 = hw - h * WW;         // multiple of 4 -> float4-aligned
    const float* xn = x + (size_t)n * CIN * HWN;
    const bool lok = (w0 > 0);
    const bool rok = (w0 < WW - 4);

    float acc[12];
#pragma unroll
    for (int i = 0; i < 12; ++i) acc[i] = 0.f;

#pragma unroll
    for (int cc = 0; cc < 4; ++cc) {
        const int c = cg * 4 + cc;
        const float* xc = xn + (size_t)c * HWN;
        float v[3][6];
#pragma unroll
        for (int r = 0; r < 3; ++r) {
            int y = h - 1 + r;
            if (y >= 0 && y < HH) {
                const float* xr = xc + y * WW + w0;
                float4 m4 = *(const float4*)xr;
                v[r][1] = m4.x; v[r][2] = m4.y; v[r][3] = m4.z; v[r][4] = m4.w;
                v[r][0] = lok ? xr[-1] : 0.f;
                v[r][5] = rok ? xr[4]  : 0.f;
            } else {
#pragma unroll
                for (int i = 0; i < 6; ++i) v[r][i] = 0.f;
            }
        }
        float wr[28];
        const float* wc = &wl[c * 28];
#pragma unroll
        for (int i2 = 0; i2 < 7; ++i2) {
            float4 q4 = *(const float4*)(wc + i2 * 4);
            wr[i2 * 4 + 0] = q4.x; wr[i2 * 4 + 1] = q4.y;
            wr[i2 * 4 + 2] = q4.z; wr[i2 * 4 + 3] = q4.w;
        }
#pragma unroll
        for (int ky = 0; ky < 3; ++ky)
#pragma unroll
            for (int kx = 0; kx < 3; ++kx) {
                const int kk = ky * 3 + kx;
                const float wj0 = wr[kk * 3 + 0];
                const float wj1 = wr[kk * 3 + 1];
                const float wj2 = wr[kk * 3 + 2];
#pragma unroll
                for (int q = 0; q < 4; ++q) {
                    float val = v[ky][q + kx];
                    acc[q * 3 + 0] = fmaf(val, wj0, acc[q * 3 + 0]);
                    acc[q * 3 + 1] = fmaf(val, wj1, acc[q * 3 + 1]);
                    acc[q * 3 + 2] = fmaf(val, wj2, acc[q * 3 + 2]);
                }
            }
    }
#pragma unroll
    for (int i = 0; i < 12; ++i) sp[cg][sl][i] = acc[i];
    __syncthreads();
    if (cg < 8) {
#pragma unroll
        for (int k = 8; k < 32; k += 8)
#pragma unroll
            for (int i = 0; i < 12; ++i) sp[cg][sl][i] += sp[cg + k][sl][i];
    }
    __syncthreads();
    if (t < 32) {
        const int s2 = t >> 2, q = t & 3;
        float b0 = b_head[0], b1 = b_head[1], b2 = b_head[2];
#pragma unroll
        for (int cgi = 0; cgi < 8; ++cgi) {
            b0 += sp[cgi][s2][q * 3 + 0];
            b1 += sp[cgi][s2][q * 3 + 1];
            b2 += sp[cgi][s2][q * 3 + 2];
        }
        int pp = b * 32 + t;
        dxv[pp]   = 0.25f * tanhf(b0);
        dyv[pp]   = 0.25f * tanhf(b1);
        maskv[pp] = 1.f / (1.f + expf(-b2));
    }
}

// ---------------------------------------------------------------- xpose:
// x[N,C,H,W] -> xt[n][hw][slot]: pixel-major, channels permuted into MFMA
// B-slot order (pairB), so dcn gathers become contiguous float4 per thread.
__global__ __launch_bounds__(256) void xpose_kernel(const float* __restrict__ x,
                                                    const int* __restrict__ pairB,
                                                    float* __restrict__ xt) {
    __shared__ float tile[CIN][XPB + 1];   // 128 x 65 floats = 33.3 KB
    __shared__ int sperm[CIN];
    const int b = blockIdx.x, t = threadIdx.x;
    const int p0 = b * XPB;                // global pixel base (XPB | HWN)
    const int n  = p0 / HWN, hw0 = p0 % HWN;
    const float* xn = x + (size_t)n * CIN * HWN + hw0;

    if (t < CIN) {
        int q = t >> 5, j = t & 31;
        sperm[t] = q * 32 + (pairB[j] & 31);
    }
    __syncthreads();

    // read: 4 reps x (32 c x 64 px), 256B contiguous per channel row
#pragma unroll
    for (int rep = 0; rep < 4; ++rep) {
        const int c  = rep * 32 + (t >> 3);
        const int px = (t & 7) * 8;
        const float* src = xn + (size_t)c * HWN + px;
        float4 a = *(const float4*)src;
        float4 bq = *(const float4*)(src + 4);
        tile[c][px + 0] = a.x;  tile[c][px + 1] = a.y;
        tile[c][px + 2] = a.z;  tile[c][px + 3] = a.w;
        tile[c][px + 4] = bq.x; tile[c][px + 5] = bq.y;
        tile[c][px + 6] = bq.z; tile[c][px + 7] = bq.w;
    }
    __syncthreads();

    // write: thread (px = t>>2, jg = t&3) -> 32 consecutive slots of one pixel
    const int px = t >> 2, jg = t & 3;
    float* dst = xt + ((size_t)p0 + px) * CIN + jg * 32;
#pragma unroll
    for (int jj = 0; jj < 32; jj += 4) {
        float4 v;
        v.x = tile[sperm[jg * 32 + jj + 0]][px];
        v.y = tile[sperm[jg * 32 + jj + 1]][px];
        v.z = tile[sperm[jg * 32 + jj + 2]][px];
        v.w = tile[sperm[jg * 32 + jj + 3]][px];
        *(float4*)(dst + jj) = v;
    }
}

// ---------------------------------------------------------------- main DCN
// Same r11 pipeline skeleton + probed layouts, but gathers now hit xt
// (pixel-major, slot-ordered): one float4 per corner instead of 4 scalars.
__global__ __launch_bounds__(256) void dcn_kernel(const float* __restrict__ xt,
                                                  const ushort* __restrict__ wah,
                                                  const float* __restrict__ dxv,
                                                  const float* __restrict__ dyv,
                                                  const float* __restrict__ maskv,
                                                  const int* __restrict__ map,
                                                  float* __restrict__ out,
                                                  float* __restrict__ gn_part) {
    __shared__ __attribute__((aligned(16))) ushort sBh[2][4 * PXB * 8];  // 4 KB
    __shared__ float sMask[PXB];
    __shared__ float gred[16];

    const int t = threadIdx.x;
    const int lane = t & 63;
    const int wv = t >> 6;
    const int lg = lane >> 4;
    const int ml = lane & 15;
    const int pix = t & 31;
    const int sg  = t >> 5;         // 0..7: slot quad sg*4..sg*4+3

    int b = blockIdx.x;
    int nb = (b & 7) * (NBLK / 8) + (b >> 3);     // XCD swizzle
    const int p0  = nb * PXB;
    const int n   = p0 / HWN;
    const int hw0 = p0 % HWN;
    const float* xtn = xt + (size_t)n * HWN * CIN;

    if (t < PXB) sMask[t] = maskv[p0 + t];
    if (t < 16) gred[t] = 0.f;

    const float dxl = dxv[p0 + pix];
    const float dyl = dyv[p0 + pix];
    const int hme = (hw0 + pix) / WW;
    const int wme = (hw0 + pix) % WW;

    f32x4 acc[2][2];
#pragma unroll
    for (int i = 0; i < 2; i++)
#pragma unroll
        for (int j = 0; j < 2; j++) acc[i][j] = (f32x4){0.f, 0.f, 0.f, 0.f};

    const int oyc[9] = {0, 0, 0, 1, 0, -1, 1, 1, -1};
    const int oxc[9] = {0, 1, -1, 0, 0, 0, 1, -1, 1};
    const int ncl[9] = {1, 2, 2, 2, 1, 2, 4, 4, 4};

    int aa[4]; float wq[4];
    float4 vr0, vr1, vr2, vr3;       // prefetched per-corner slot quads
    bf16x8 An0, An1;                 // prefetched A frags

    // ---- prologue: corners tap0, issue chunk(0,0) gathers + A frags
    {
        float py = (float)(hme - 1), px = (float)(wme - 1);
        float fy0 = floorf(py), fx0 = floorf(px);
        int y0 = (int)fy0, x0 = (int)fx0;
        float fy = py - fy0, fx = px - fx0;
#pragma unroll
        for (int j = 0; j < 4; ++j) {
            int yy = y0 + (j >> 1), xx = x0 + (j & 1);
            float wb = ((j >> 1) ? fy : 1.f - fy) * ((j & 1) ? fx : 1.f - fx);
            bool ok = (yy >= 0) && (yy < HH) && (xx >= 0) && (xx < WW);
            aa[j] = min(max(yy, 0), HH - 1) * WW + min(max(xx, 0), WW - 1);
            wq[j] = ok ? wb : 0.f;
        }
        vr0 = *(const float4*)(xtn + ((aa[0] << 7) + sg * 4));   // q=0
        const size_t abase = (size_t)(wv * 2) * 512 + lane * 8;
        An0 = *(const bf16x8*)(wah + abase);
        An1 = *(const bf16x8*)(wah + abase + 512);
    }

#pragma unroll
    for (int j = 0; j < 36; ++j) {
        const int k = j >> 2;
        const int NC = ncl[k];
        bf16x8 Ah0 = An0, Ah1 = An1;
        // ---- pack set j (waits on j's gathers — issued one iteration ago)
        union { short4 v; ushort u[4]; } hv;
        {
            float s0 = vr0.x * wq[0], s1 = vr0.y * wq[0];
            float s2 = vr0.z * wq[0], s3 = vr0.w * wq[0];
            if (NC >= 2) {
                s0 = fmaf(vr1.x, wq[1], s0); s1 = fmaf(vr1.y, wq[1], s1);
                s2 = fmaf(vr1.z, wq[1], s2); s3 = fmaf(vr1.w, wq[1], s3);
            }
            if (NC == 4) {
                s0 = fmaf(vr2.x, wq[2], s0); s1 = fmaf(vr2.y, wq[2], s1);
                s2 = fmaf(vr2.z, wq[2], s2); s3 = fmaf(vr2.w, wq[2], s3);
                s0 = fmaf(vr3.x, wq[3], s0); s1 = fmaf(vr3.y, wq[3], s1);
                s2 = fmaf(vr3.z, wq[3], s2); s3 = fmaf(vr3.w, wq[3], s3);
            }
            hv.u[0] = f2bf(s0); hv.u[1] = f2bf(s1);
            hv.u[2] = f2bf(s2); hv.u[3] = f2bf(s3);
        }
        const int wbase = ((sg >> 1) * PXB + pix) * 8 + (sg & 1) * 4;
        *(short4*)&sBh[j & 1][wbase] = hv.v;
        // ---- prefetch set j+1 (global loads stay in flight across the barrier)
        if (j < 35) {
            const int jn = j + 1, kn = jn >> 2, qn = jn & 3;
            if (qn == 0) {
                const int ky = kn / 3, kx = kn - ky * 3;
                float py = (float)(hme - 1 + ky) + (float)oyc[kn] * dxl;
                float px = (float)(wme - 1 + kx) + (float)oxc[kn] * dyl;
                float fy0 = floorf(py), fx0 = floorf(px);
                int y0 = (int)fy0, x0 = (int)fx0;
                float fy = py - fy0, fx = px - fx0;
#pragma unroll
                for (int jj = 0; jj < 4; ++jj) {
                    int yy = y0 + (jj >> 1), xx = x0 + (jj & 1);
                    float wb = ((jj >> 1) ? fy : 1.f - fy) * ((jj & 1) ? fx : 1.f - fx);
                    bool ok = (yy >= 0) && (yy < HH) && (xx >= 0) && (xx < WW);
                    aa[jj] = min(max(yy, 0), HH - 1) * WW + min(max(xx, 0), WW - 1);
                    wq[jj] = ok ? wb : 0.f;
                }
                if (ncl[kn] == 2 && oxc[kn] == 0) { aa[1] = aa[2]; wq[1] = wq[2]; }
            }
            const int NCn = ncl[kn];
            const int co = qn * 32 + sg * 4;
            vr0 = *(const float4*)(xtn + ((aa[0] << 7) + co));
            if (NCn >= 2) vr1 = *(const float4*)(xtn + ((aa[1] << 7) + co));
            if (NCn == 4) {
                vr2 = *(const float4*)(xtn + ((aa[2] << 7) + co));
                vr3 = *(const float4*)(xtn + ((aa[3] << 7) + co));
            }
            const size_t abase = (size_t)((kn * 4 + qn) * 8 + wv * 2) * 512 + lane * 8;
            An0 = *(const bf16x8*)(wah + abase);
            An1 = *(const bf16x8*)(wah + abase + 512);
        }
        barrier_keep_vm();   // drains LDS writes; gathers stay outstanding
        // ---- MFMAs on buf[j&1]
#pragma unroll
        for (int pt = 0; pt < 2; ++pt) {
            const int rbase = (lg * PXB + pt * 16 + ml) * 8;
            bf16x8 Bh = *(const bf16x8*)&sBh[j & 1][rbase];
            acc[0][pt] = __builtin_amdgcn_mfma_f32_16x16x32_bf16(Ah0, Bh, acc[0][pt], 0, 0, 0);
            acc[1][pt] = __builtin_amdgcn_mfma_f32_16x16x32_bf16(Ah1, Bh, acc[1][pt], 0, 0, 0);
        }
    }

    // ---- epilogue: mask, scatter via probed D layout, GN partials (r8-proven)
    int4 mn4 = *(const int4*)&map[lane * 4];
    int mn[4] = {mn4.x, mn4.y, mn4.z, mn4.w};
    float s1g[2] = {0.f, 0.f}, s2g[2] = {0.f, 0.f};
#pragma unroll
    for (int ot = 0; ot < 2; ++ot) {
        int otile = wv * 32 + ot * 16;
#pragma unroll
        for (int pt = 0; pt < 2; ++pt) {
#pragma unroll
            for (int r = 0; r < 4; ++r) {
                int m = mn[r] >> 4, nn2 = mn[r] & 15;
                int p = pt * 16 + nn2;
                float v = acc[ot][pt][r] * sMask[p];
                s1g[ot] += v;
                s2g[ot] += v * v;
                out[((size_t)n * COUT + otile + m) * HWN + hw0 + p] = v;
            }
        }
    }
#pragma unroll
    for (int ot = 0; ot < 2; ++ot) {
        int g = wv * 2 + ot;
        atomicAdd(&gred[g * 2 + 0], s1g[ot]);
        atomicAdd(&gred[g * 2 + 1], s2g[ot]);
    }
    __syncthreads();
    if (t < 8) {
        atomicAdd(&gn_part[n * 8 + t],      gred[t * 2 + 0]);
        atomicAdd(&gn_part[64 + n * 8 + t], gred[t * 2 + 1]);
    }
}

// ---------------------------------------------------------------- GN apply (stats inline)
__global__ __launch_bounds__(256) void gn_apply(float* __restrict__ out,
                                                const float* __restrict__ gn_part,
                                                const float* __restrict__ gamma,
                                                const float* __restrict__ beta) {
    int i4 = blockIdx.x * 256 + threadIdx.x;
    size_t e = (size_t)i4 * 4;
    int og = (int)(e / HWN);
    int n = og >> 7, o = og & 127;
    int s = n * 8 + (o >> 4);
    const float cnt = (float)GSZ * (float)HWN;
    float s1 = gn_part[s], s2 = gn_part[64 + s];
    float mu = s1 / cnt;
    float var = s2 / cnt - mu * mu;
    float inv = rsqrtf(var + 1e-5f);
    float ga = gamma[o] * inv;
    float be = beta[o] - mu * ga;
    float4 v = *(float4*)(out + e);
    v.x = fmaxf(fmaf(v.x, ga, be), 0.f);
    v.y = fmaxf(fmaf(v.y, ga, be), 0.f);
    v.z = fmaxf(fmaf(v.z, ga, be), 0.f);
    v.w = fmaxf(fmaf(v.w, ga, be), 0.f);
    *(float4*)(out + e) = v;
}

// ---------------------------------------------------------------- launch
extern "C" void kernel_launch(void* const* d_in, const int* in_sizes, int n_in,
                              void* d_out, int out_size, void* d_ws, size_t ws_size,
                              hipStream_t stream) {
    const float* x       = (const float*)d_in[0];
    const float* w_head  = (const float*)d_in[1];
    const float* b_head  = (const float*)d_in[2];
    const float* w_dcn   = (const float*)d_in[3];
    const float* gamma   = (const float*)d_in[4];
    const float* beta    = (const float*)d_in[5];
    float* out = (float*)d_out;
    float* ws  = (float*)d_ws;

    ushort* wah    = (ushort*)(ws + OFF_WAH);
    float* dxv     = ws + OFF_DX;
    float* dyv     = ws + OFF_DY;
    float* maskv   = ws + OFF_MASK;
    float* gn_part = ws + OFF_GN;
    int*   map     = (int*)(ws + OFF_MAP);
    int*   pairB   = (int*)(ws + OFF_PAIR);
    float* xt      = ws + OFF_XT;

    pre_kernel<<<HEADB + 576, 256, 0, stream>>>(x, w_head, b_head, w_dcn, wah,
                                                dxv, dyv, maskv, gn_part, map, pairB);
    xpose_kernel<<<NHW / XPB, 256, 0, stream>>>(x, pairB, xt);
    dcn_kernel<<<NBLK, 256, 0, stream>>>(xt, wah, dxv, dyv, maskv, map, out, gn_part);
    gn_apply<<<(NB * COUT * HWN) / 4 / 256, 256, 0, stream>>>(out, gn_part, gamma, beta);
}

// Round 3
// 159.622 us; speedup vs baseline: 1.2285x; 1.2174x over previous
//
#include <hip/hip_runtime.h>
#include <hip/hip_bf16.h>
#include <math.h>

#define NB   4
#define CIN  128
#define HH   96
#define WW   96
#define HWN  (HH*WW)        // 9216
#define NHW  (NB*HWN)       // 36864
#define COUT 128
#define KW   9
#define KDIM (CIN*KW)       // 1152
#define GSZ  16
#define PXB  32             // pixels per dcn block
#define NBLK (NHW/PXB)      // 1152
#define XPB  64             // pixels per xpose block
#define XPOB (NHW/XPB)      // 576 xpose blocks

typedef __attribute__((ext_vector_type(8))) short bf16x8;   // 8 bf16 (4 VGPRs)
typedef __attribute__((ext_vector_type(4))) float f32x4;    // 4 fp32 acc

// ws layout (float units)
#define OFF_WAH   0          // 73728 floats = 147456 ushorts: W hi, A-frag identity order
#define OFF_DX    147456
#define OFF_DY    184320
#define OFF_MASK  221184
#define OFF_GN    258048     // 128: s1[64], s2[64]
#define OFF_MAP   258240     // 256 ints: D-layout map[lane*4+reg] = (m<<4)|n
#define OFF_PAIR  258496     // 32 ints: B-slot j holds channel pairB[j]
#define OFF_XT    258560     // 4718592 floats: xt[n][hw][slot-permuted c] (19 MB)

#define HEADB 1152           // head blocks in pre_kernel (8 slots x 32 cgs each)

__device__ __forceinline__ ushort f2bf(float f) {
    union { float f; uint u; } v; v.f = f;
    uint r = v.u + 0x7fffu + ((v.u >> 16) & 1u);   // RNE to bf16
    return (ushort)(r >> 16);
}

// Workgroup barrier that drains LDS ops but leaves global loads in flight
// (r9/r11-proven correct).
__device__ __forceinline__ void barrier_keep_vm() {
    asm volatile("s_waitcnt lgkmcnt(0)\n\ts_barrier" ::: "memory");
}

// ------------------------------------------------- pre:
//   b <  HEADB                : head conv (sliding window)
//   HEADB <= b < HEADB+576    : wsplit + map/pairB probes (r8-proven)
//   b >= HEADB+576            : xpose (local pairing probe, coalesced writes)
__global__ __launch_bounds__(256) void pre_kernel(const float* __restrict__ x,
                                                  const float* __restrict__ w_head,
                                                  const float* __restrict__ b_head,
                                                  const float* __restrict__ wd,
                                                  ushort* __restrict__ wah,
                                                  float* __restrict__ dxv,
                                                  float* __restrict__ dyv,
                                                  float* __restrict__ maskv,
                                                  float* __restrict__ gn_part,
                                                  int* __restrict__ map,
                                                  int* __restrict__ pairB,
                                                  float* __restrict__ xt) {
    __shared__ __attribute__((aligned(16))) float smem[8480];   // 33.9 KB, aliased per branch
    const int b = blockIdx.x, t = threadIdx.x;

    if (b >= HEADB + 576) {
        // ---------------- xpose part: x[N,C,H,W] -> xt[n][hw][slot]
        float (*tile)[XPB + 1] = (float (*)[XPB + 1])smem;       // 128 x 65
        int* sperm = (int*)(smem + CIN * (XPB + 1));             // 128
        int* spair = (int*)(smem + CIN * (XPB + 1) + CIN);       // 32
        const int bb2 = b - (HEADB + 576);
        const int p0 = bb2 * XPB;
        const int n  = p0 / HWN, hw0 = p0 % HWN;
        const float* xn = x + (size_t)n * CIN * HWN + hw0;

        // local pairing probe (exact copy of r6-proven probe, LDS result)
        if (t < 64) {
            int l = t;
            union { bf16x8 v; short a[8]; } B;
#pragma unroll
            for (int e = 0; e < 8; ++e) {
                float val = (float)(1u << (((l >> 4) * 8 + e) & 31));
                B.a[e] = (short)f2bf(val);
            }
#pragma unroll
            for (int s = 0; s < 32; ++s) {
                union { bf16x8 v; short a[8]; } A;
#pragma unroll
                for (int e = 0; e < 8; ++e) A.a[e] = 0;
                if ((l >> 4) == (s >> 3)) A.a[s & 7] = (short)f2bf(1.0f);
                f32x4 d = {0.f, 0.f, 0.f, 0.f};
                d = __builtin_amdgcn_mfma_f32_16x16x32_bf16(A.v, B.v, d, 0, 0, 0);
                float v0 = d[0];
                if (l == 0 && v0 > 0.f) {
                    int ex; frexpf(v0, &ex);     // v0 = 2^j -> ex = j+1
                    int j = ex - 1;
                    if (j >= 0 && j < 32) spair[j] = s;
                }
            }
        }
        __syncthreads();
        if (t < CIN) sperm[t] = (t & ~31) | (spair[t & 31] & 31);
        __syncthreads();

        // read: 4 reps x (32 c x 64 px), 32B contiguous per thread
#pragma unroll
        for (int rep = 0; rep < 4; ++rep) {
            const int c  = rep * 32 + (t >> 3);
            const int px = (t & 7) * 8;
            const float* src = xn + (size_t)c * HWN + px;
            float4 a = *(const float4*)src;
            float4 bq = *(const float4*)(src + 4);
            tile[c][px + 0] = a.x;  tile[c][px + 1] = a.y;
            tile[c][px + 2] = a.z;  tile[c][px + 3] = a.w;
            tile[c][px + 4] = bq.x; tile[c][px + 5] = bq.y;
            tile[c][px + 6] = bq.z; tile[c][px + 7] = bq.w;
        }
        __syncthreads();

        // write: chunk c: lane-minor over slot4 -> 2 x 512B contiguous per wave
#pragma unroll
        for (int wc = 0; wc < 8; ++wc) {
            const int idx = wc * 256 + t;       // 0..2047
            const int px  = idx >> 5;           // 0..63
            const int s4  = idx & 31;           // slot quad
            float4 v;
            v.x = tile[sperm[s4 * 4 + 0]][px];
            v.y = tile[sperm[s4 * 4 + 1]][px];
            v.z = tile[sperm[s4 * 4 + 2]][px];
            v.w = tile[sperm[s4 * 4 + 3]][px];
            *(float4*)(xt + ((size_t)(p0 + px)) * CIN + s4 * 4) = v;
        }
        return;
    }

    if (b >= HEADB) {
        // ---------------- wsplit part (r8-proven indexing), hi only
        const int bb = b - HEADB;
        int i = bb * 256 + t;                     // < 147456
        {
            int e  = i & 7;
            int l  = (i >> 3) & 63;
            int ot = (i >> 9) & 7;
            int q  = (i >> 12) & 3;
            int k  = i >> 14;                     // 0..8
            int o  = ot * 16 + (l & 15);
            int c  = q * 32 + (l >> 4) * 8 + e;
            wah[i] = f2bf(wd[o * KDIM + c * KW + k]);
        }
        if (bb == 0 && t < 128) gn_part[t] = 0.f;
        if (bb == 0 && t < 64) {
            // D-layout probe (HW-verified r4/r6)
            int l = t;
            bf16x8 A1 = {}, B1 = {}, A2 = {}, B2 = {};
            if ((l >> 4) == 0) {
                A1[0] = (short)f2bf((float)((l & 15) + 1));
                B1[0] = (short)f2bf(1.0f);
                A2[0] = (short)f2bf(1.0f);
                B2[0] = (short)f2bf((float)((l & 15) + 1));
            }
            f32x4 d1 = {0.f,0.f,0.f,0.f}, d2 = {0.f,0.f,0.f,0.f};
            d1 = __builtin_amdgcn_mfma_f32_16x16x32_bf16(A1, B1, d1, 0, 0, 0);
            d2 = __builtin_amdgcn_mfma_f32_16x16x32_bf16(A2, B2, d2, 0, 0, 0);
#pragma unroll
            for (int r = 0; r < 4; ++r) {
                int m = (int)(d1[r] + 0.5f) - 1;
                int n = (int)(d2[r] + 0.5f) - 1;
                map[l * 4 + r] = (m << 4) | n;
            }
        }
        if (bb == 1 && t < 64) {
            // global pairB probe (kept for ws-layout stability)
            int l = t;
            union { bf16x8 v; short a[8]; } B;
#pragma unroll
            for (int e = 0; e < 8; ++e) {
                float val = (float)(1u << (((l >> 4) * 8 + e) & 31));
                B.a[e] = (short)f2bf(val);
            }
#pragma unroll
            for (int s = 0; s < 32; ++s) {
                union { bf16x8 v; short a[8]; } A;
#pragma unroll
                for (int e = 0; e < 8; ++e) A.a[e] = 0;
                if ((l >> 4) == (s >> 3)) A.a[s & 7] = (short)f2bf(1.0f);
                f32x4 d = {0.f, 0.f, 0.f, 0.f};
                d = __builtin_amdgcn_mfma_f32_16x16x32_bf16(A.v, B.v, d, 0, 0, 0);
                float v0 = d[0];
                if (l == 0 && v0 > 0.f) {
                    int ex; frexpf(v0, &ex);     // v0 = 2^j -> ex = j+1
                    int j = ex - 1;
                    if (j >= 0 && j < 32) pairB[j] = s;
                }
            }
        }
        return;
    }

    // ---------------- head v2 (sliding-window conv)
    float* wl = smem;                                    // CIN*28 = 3584
    float (*sp)[8][13] = (float (*)[8][13])(smem + CIN * 28);   // 32*8*13 = 3328
    for (int i = t; i < 3456; i += 256) {
        int j = i / KDIM, r = i - j * KDIM;
        int c = r / 9, kk = r - c * 9;
        wl[c * 28 + kk * 3 + j] = w_head[i];
    }
    __syncthreads();

    const int sl = t & 7;               // slot in block (4 px each)
    const int cg = t >> 3;              // 0..31, 4 channels each
    const int p0 = b * 32 + sl * 4;     // first pixel of slot
    const int n  = p0 / HWN;
    const int hw = p0 - n * HWN;
    const int h  = hw / WW;
    const int w0 = hw - h * WW;         // multiple of 4 -> float4-aligned
    const float* xn = x + (size_t)n * CIN * HWN;
    const bool lok = (w0 > 0);
    const bool rok = (w0 < WW - 4);

    float acc[12];
#pragma unroll
    for (int i = 0; i < 12; ++i) acc[i] = 0.f;

#pragma unroll
    for (int cc = 0; cc < 4; ++cc) {
        const int c = cg * 4 + cc;
        const float* xc = xn + (size_t)c * HWN;
        float v[3][6];
#pragma unroll
        for (int r = 0; r < 3; ++r) {
            int y = h - 1 + r;
            if (y >= 0 && y < HH) {
                const float* xr = xc + y * WW + w0;
                float4 m4 = *(const float4*)xr;
                v[r][1] = m4.x; v[r][2] = m4.y; v[r][3] = m4.z; v[r][4] = m4.w;
                v[r][0] = lok ? xr[-1] : 0.f;
                v[r][5] = rok ? xr[4]  : 0.f;
            } else {
#pragma unroll
                for (int i = 0; i < 6; ++i) v[r][i] = 0.f;
            }
        }
        float wr[28];
        const float* wc = &wl[c * 28];
#pragma unroll
        for (int i2 = 0; i2 < 7; ++i2) {
            float4 q4 = *(const float4*)(wc + i2 * 4);
            wr[i2 * 4 + 0] = q4.x; wr[i2 * 4 + 1] = q4.y;
            wr[i2 * 4 + 2] = q4.z; wr[i2 * 4 + 3] = q4.w;
        }
#pragma unroll
        for (int ky = 0; ky < 3; ++ky)
#pragma unroll
            for (int kx = 0; kx < 3; ++kx) {
                const int kk = ky * 3 + kx;
                const float wj0 = wr[kk * 3 + 0];
                const float wj1 = wr[kk * 3 + 1];
                const float wj2 = wr[kk * 3 + 2];
#pragma unroll
                for (int q = 0; q < 4; ++q) {
                    float val = v[ky][q + kx];
                    acc[q * 3 + 0] = fmaf(val, wj0, acc[q * 3 + 0]);
                    acc[q * 3 + 1] = fmaf(val, wj1, acc[q * 3 + 1]);
                    acc[q * 3 + 2] = fmaf(val, wj2, acc[q * 3 + 2]);
                }
            }
    }
#pragma unroll
    for (int i = 0; i < 12; ++i) sp[cg][sl][i] = acc[i];
    __syncthreads();
    if (cg < 8) {
#pragma unroll
        for (int k = 8; k < 32; k += 8)
#pragma unroll
            for (int i = 0; i < 12; ++i) sp[cg][sl][i] += sp[cg + k][sl][i];
    }
    __syncthreads();
    if (t < 32) {
        const int s2 = t >> 2, q = t & 3;
        float b0 = b_head[0], b1 = b_head[1], b2 = b_head[2];
#pragma unroll
        for (int cgi = 0; cgi < 8; ++cgi) {
            b0 += sp[cgi][s2][q * 3 + 0];
            b1 += sp[cgi][s2][q * 3 + 1];
            b2 += sp[cgi][s2][q * 3 + 2];
        }
        int pp = b * 32 + t;
        dxv[pp]   = 0.25f * tanhf(b0);
        dyv[pp]   = 0.25f * tanhf(b1);
        maskv[pp] = 1.f / (1.f + expf(-b2));
    }
}

// ---------------------------------------------------------------- main DCN
// r11 pipeline skeleton + xt gathers. Lane remap this round: pix = t>>3,
// sg = t&7 -> 8 adjacent lanes read 128B contiguous per gather (2x fewer
// L1 transactions). LDS layout keyed on (sg,pix) values: unchanged.
__global__ __launch_bounds__(256) void dcn_kernel(const float* __restrict__ xt,
                                                  const ushort* __restrict__ wah,
                                                  const float* __restrict__ dxv,
                                                  const float* __restrict__ dyv,
                                                  const float* __restrict__ maskv,
                                                  const int* __restrict__ map,
                                                  float* __restrict__ out,
                                                  float* __restrict__ gn_part) {
    __shared__ __attribute__((aligned(16))) ushort sBh[2][4 * PXB * 8];  // 4 KB
    __shared__ float sMask[PXB];
    __shared__ float gred[16];

    const int t = threadIdx.x;
    const int lane = t & 63;
    const int wv = t >> 6;
    const int lg = lane >> 4;
    const int ml = lane & 15;
    const int pix = t >> 3;         // 0..31 (8 adjacent lanes share a pixel)
    const int sg  = t & 7;          // slot quad sg*4..sg*4+3

    int b = blockIdx.x;
    int nb = (b & 7) * (NBLK / 8) + (b >> 3);     // XCD swizzle
    const int p0  = nb * PXB;
    const int n   = p0 / HWN;
    const int hw0 = p0 % HWN;
    const float* xtn = xt + (size_t)n * HWN * CIN;

    if (t < PXB) sMask[t] = maskv[p0 + t];
    if (t < 16) gred[t] = 0.f;

    const float dxl = dxv[p0 + pix];
    const float dyl = dyv[p0 + pix];
    const int hme = (hw0 + pix) / WW;
    const int wme = (hw0 + pix) % WW;

    f32x4 acc[2][2];
#pragma unroll
    for (int i = 0; i < 2; i++)
#pragma unroll
        for (int j = 0; j < 2; j++) acc[i][j] = (f32x4){0.f, 0.f, 0.f, 0.f};

    const int oyc[9] = {0, 0, 0, 1, 0, -1, 1, 1, -1};
    const int oxc[9] = {0, 1, -1, 0, 0, 0, 1, -1, 1};
    const int ncl[9] = {1, 2, 2, 2, 1, 2, 4, 4, 4};

    int aa[4]; float wq[4];
    float4 vr0, vr1, vr2, vr3;       // prefetched per-corner slot quads
    bf16x8 An0, An1;                 // prefetched A frags

    // ---- prologue: corners tap0, issue chunk(0,0) gathers + A frags
    {
        float py = (float)(hme - 1), px = (float)(wme - 1);
        float fy0 = floorf(py), fx0 = floorf(px);
        int y0 = (int)fy0, x0 = (int)fx0;
        float fy = py - fy0, fx = px - fx0;
#pragma unroll
        for (int j = 0; j < 4; ++j) {
            int yy = y0 + (j >> 1), xx = x0 + (j & 1);
            float wb = ((j >> 1) ? fy : 1.f - fy) * ((j & 1) ? fx : 1.f - fx);
            bool ok = (yy >= 0) && (yy < HH) && (xx >= 0) && (xx < WW);
            aa[j] = min(max(yy, 0), HH - 1) * WW + min(max(xx, 0), WW - 1);
            wq[j] = ok ? wb : 0.f;
        }
        vr0 = *(const float4*)(xtn + ((aa[0] << 7) + sg * 4));   // q=0
        const size_t abase = (size_t)(wv * 2) * 512 + lane * 8;
        An0 = *(const bf16x8*)(wah + abase);
        An1 = *(const bf16x8*)(wah + abase + 512);
    }

#pragma unroll
    for (int j = 0; j < 36; ++j) {
        const int k = j >> 2;
        const int NC = ncl[k];
        bf16x8 Ah0 = An0, Ah1 = An1;
        // ---- pack set j (waits on j's gathers — issued one iteration ago)
        union { short4 v; ushort u[4]; } hv;
        {
            float s0 = vr0.x * wq[0], s1 = vr0.y * wq[0];
            float s2 = vr0.z * wq[0], s3 = vr0.w * wq[0];
            if (NC >= 2) {
                s0 = fmaf(vr1.x, wq[1], s0); s1 = fmaf(vr1.y, wq[1], s1);
                s2 = fmaf(vr1.z, wq[1], s2); s3 = fmaf(vr1.w, wq[1], s3);
            }
            if (NC == 4) {
                s0 = fmaf(vr2.x, wq[2], s0); s1 = fmaf(vr2.y, wq[2], s1);
                s2 = fmaf(vr2.z, wq[2], s2); s3 = fmaf(vr2.w, wq[2], s3);
                s0 = fmaf(vr3.x, wq[3], s0); s1 = fmaf(vr3.y, wq[3], s1);
                s2 = fmaf(vr3.z, wq[3], s2); s3 = fmaf(vr3.w, wq[3], s3);
            }
            hv.u[0] = f2bf(s0); hv.u[1] = f2bf(s1);
            hv.u[2] = f2bf(s2); hv.u[3] = f2bf(s3);
        }
        const int wbase = ((sg >> 1) * PXB + pix) * 8 + (sg & 1) * 4;
        *(short4*)&sBh[j & 1][wbase] = hv.v;
        // ---- prefetch set j+1 (global loads stay in flight across the barrier)
        if (j < 35) {
            const int jn = j + 1, kn = jn >> 2, qn = jn & 3;
            if (qn == 0) {
                const int ky = kn / 3, kx = kn - ky * 3;
                float py = (float)(hme - 1 + ky) + (float)oyc[kn] * dxl;
                float px = (float)(wme - 1 + kx) + (float)oxc[kn] * dyl;
                float fy0 = floorf(py), fx0 = floorf(px);
                int y0 = (int)fy0, x0 = (int)fx0;
                float fy = py - fy0, fx = px - fx0;
#pragma unroll
                for (int jj = 0; jj < 4; ++jj) {
                    int yy = y0 + (jj >> 1), xx = x0 + (jj & 1);
                    float wb = ((jj >> 1) ? fy : 1.f - fy) * ((jj & 1) ? fx : 1.f - fx);
                    bool ok = (yy >= 0) && (yy < HH) && (xx >= 0) && (xx < WW);
                    aa[jj] = min(max(yy, 0), HH - 1) * WW + min(max(xx, 0), WW - 1);
                    wq[jj] = ok ? wb : 0.f;
                }
                if (ncl[kn] == 2 && oxc[kn] == 0) { aa[1] = aa[2]; wq[1] = wq[2]; }
            }
            const int NCn = ncl[kn];
            const int co = qn * 32 + sg * 4;
            vr0 = *(const float4*)(xtn + ((aa[0] << 7) + co));
            if (NCn >= 2) vr1 = *(const float4*)(xtn + ((aa[1] << 7) + co));
            if (NCn == 4) {
                vr2 = *(const float4*)(xtn + ((aa[2] << 7) + co));
                vr3 = *(const float4*)(xtn + ((aa[3] << 7) + co));
            }
            const size_t abase = (size_t)((kn * 4 + qn) * 8 + wv * 2) * 512 + lane * 8;
            An0 = *(const bf16x8*)(wah + abase);
            An1 = *(const bf16x8*)(wah + abase + 512);
        }
        barrier_keep_vm();   // drains LDS writes; gathers stay outstanding
        // ---- MFMAs on buf[j&1]
#pragma unroll
        for (int pt = 0; pt < 2; ++pt) {
            const int rbase = (lg * PXB + pt * 16 + ml) * 8;
            bf16x8 Bh = *(const bf16x8*)&sBh[j & 1][rbase];
            acc[0][pt] = __builtin_amdgcn_mfma_f32_16x16x32_bf16(Ah0, Bh, acc[0][pt], 0, 0, 0);
            acc[1][pt] = __builtin_amdgcn_mfma_f32_16x16x32_bf16(Ah1, Bh, acc[1][pt], 0, 0, 0);
        }
    }

    // ---- epilogue: mask, scatter via probed D layout, GN partials (r8-proven)
    int4 mn4 = *(const int4*)&map[lane * 4];
    int mn[4] = {mn4.x, mn4.y, mn4.z, mn4.w};
    float s1g[2] = {0.f, 0.f}, s2g[2] = {0.f, 0.f};
#pragma unroll
    for (int ot = 0; ot < 2; ++ot) {
        int otile = wv * 32 + ot * 16;
#pragma unroll
        for (int pt = 0; pt < 2; ++pt) {
#pragma unroll
            for (int r = 0; r < 4; ++r) {
                int m = mn[r] >> 4, nn2 = mn[r] & 15;
                int p = pt * 16 + nn2;
                float v = acc[ot][pt][r] * sMask[p];
                s1g[ot] += v;
                s2g[ot] += v * v;
                out[((size_t)n * COUT + otile + m) * HWN + hw0 + p] = v;
            }
        }
    }
#pragma unroll
    for (int ot = 0; ot < 2; ++ot) {
        int g = wv * 2 + ot;
        atomicAdd(&gred[g * 2 + 0], s1g[ot]);
        atomicAdd(&gred[g * 2 + 1], s2g[ot]);
    }
    __syncthreads();
    if (t < 8) {
        atomicAdd(&gn_part[n * 8 + t],      gred[t * 2 + 0]);
        atomicAdd(&gn_part[64 + n * 8 + t], gred[t * 2 + 1]);
    }
}

// ---------------------------------------------------------------- GN apply (stats inline)
__global__ __launch_bounds__(256) void gn_apply(float* __restrict__ out,
                                                const float* __restrict__ gn_part,
                                                const float* __restrict__ gamma,
                                                const float* __restrict__ beta) {
    int i4 = blockIdx.x * 256 + threadIdx.x;
    size_t e = (size_t)i4 * 4;
    int og = (int)(e / HWN);
    int n = og >> 7, o = og & 127;
    int s = n * 8 + (o >> 4);
    const float cnt = (float)GSZ * (float)HWN;
    float s1 = gn_part[s], s2 = gn_part[64 + s];
    float mu = s1 / cnt;
    float var = s2 / cnt - mu * mu;
    float inv = rsqrtf(var + 1e-5f);
    float ga = gamma[o] * inv;
    float be = beta[o] - mu * ga;
    float4 v = *(float4*)(out + e);
    v.x = fmaxf(fmaf(v.x, ga, be), 0.f);
    v.y = fmaxf(fmaf(v.y, ga, be), 0.f);
    v.z = fmaxf(fmaf(v.z, ga, be), 0.f);
    v.w = fmaxf(fmaf(v.w, ga, be), 0.f);
    *(float4*)(out + e) = v;
}

// ---------------------------------------------------------------- launch
extern "C" void kernel_launch(void* const* d_in, const int* in_sizes, int n_in,
                              void* d_out, int out_size, void* d_ws, size_t ws_size,
                              hipStream_t stream) {
    const float* x       = (const float*)d_in[0];
    const float* w_head  = (const float*)d_in[1];
    const float* b_head  = (const float*)d_in[2];
    const float* w_dcn   = (const float*)d_in[3];
    const float* gamma   = (const float*)d_in[4];
    const float* beta    = (const float*)d_in[5];
    float* out = (float*)d_out;
    float* ws  = (float*)d_ws;

    ushort* wah    = (ushort*)(ws + OFF_WAH);
    float* dxv     = ws + OFF_DX;
    float* dyv     = ws + OFF_DY;
    float* maskv   = ws + OFF_MASK;
    float* gn_part = ws + OFF_GN;
    int*   map     = (int*)(ws + OFF_MAP);
    int*   pairB   = (int*)(ws + OFF_PAIR);
    float* xt      = ws + OFF_XT;

    pre_kernel<<<HEADB + 576 + XPOB, 256, 0, stream>>>(x, w_head, b_head, w_dcn, wah,
                                                       dxv, dyv, maskv, gn_part, map, pairB, xt);
    dcn_kernel<<<NBLK, 256, 0, stream>>>(xt, wah, dxv, dyv, maskv, map, out, gn_part);
    gn_apply<<<(NB * COUT * HWN) / 4 / 256, 256, 0, stream>>>(out, gn_part, gamma, beta);
}

// Round 4
// 157.905 us; speedup vs baseline: 1.2419x; 1.0109x over previous
//
#include <hip/hip_runtime.h>
#include <hip/hip_bf16.h>
#include <math.h>

#define NB   4
#define CIN  128
#define HH   96
#define WW   96
#define HWN  (HH*WW)        // 9216
#define NHW  (NB*HWN)       // 36864
#define COUT 128
#define KW   9
#define KDIM (CIN*KW)       // 1152
#define GSZ  16
#define PXB  32             // pixels per dcn block
#define NBLK (NHW/PXB)      // 1152
#define XPB  64             // pixels per xpose block
#define XPOB (NHW/XPB)      // 576 xpose blocks

typedef __attribute__((ext_vector_type(8))) short bf16x8;   // 8 bf16 (4 VGPRs)
typedef __attribute__((ext_vector_type(4))) float f32x4;    // 4 fp32 acc

// ws layout (float units)
#define OFF_WAH   0          // 73728 floats = 147456 ushorts: W hi, A-frag identity order
#define OFF_DX    147456
#define OFF_DY    184320
#define OFF_MASK  221184
#define OFF_GN    258048     // 128: s1[64], s2[64]
#define OFF_MAP   258240     // 256 ints: D-layout map[lane*4+reg] = (m<<4)|n
#define OFF_PAIR  258496     // 32 ints: B-slot j holds channel pairB[j]
#define OFF_XT    258560     // 4718592 floats: xt[n][hw][slot-permuted c] (19 MB)

#define HEADB 1152           // head blocks in pre_kernel (8 slots x 32 cgs each)

__device__ __forceinline__ ushort f2bf(float f) {
    union { float f; uint u; } v; v.f = f;
    uint r = v.u + 0x7fffu + ((v.u >> 16) & 1u);   // RNE to bf16
    return (ushort)(r >> 16);
}

// Workgroup barrier that drains LDS ops but leaves global loads in flight
// (r9/r11-proven correct).
__device__ __forceinline__ void barrier_keep_vm() {
    asm volatile("s_waitcnt lgkmcnt(0)\n\ts_barrier" ::: "memory");
}

// ------------------------------------------------- pre:
//   b <  HEADB                : head conv (sliding window)
//   HEADB <= b < HEADB+576    : wsplit + map/pairB probes (r8-proven)
//   b >= HEADB+576            : xpose (local pairing probe, coalesced writes)
__global__ __launch_bounds__(256) void pre_kernel(const float* __restrict__ x,
                                                  const float* __restrict__ w_head,
                                                  const float* __restrict__ b_head,
                                                  const float* __restrict__ wd,
                                                  ushort* __restrict__ wah,
                                                  float* __restrict__ dxv,
                                                  float* __restrict__ dyv,
                                                  float* __restrict__ maskv,
                                                  float* __restrict__ gn_part,
                                                  int* __restrict__ map,
                                                  int* __restrict__ pairB,
                                                  float* __restrict__ xt) {
    __shared__ __attribute__((aligned(16))) float smem[8480];   // 33.9 KB, aliased per branch
    const int b = blockIdx.x, t = threadIdx.x;

    if (b >= HEADB + 576) {
        // ---------------- xpose part: x[N,C,H,W] -> xt[n][hw][slot]
        float (*tile)[XPB + 1] = (float (*)[XPB + 1])smem;       // 128 x 65
        int* sperm = (int*)(smem + CIN * (XPB + 1));             // 128
        int* spair = (int*)(smem + CIN * (XPB + 1) + CIN);       // 32
        const int bb2 = b - (HEADB + 576);
        const int p0 = bb2 * XPB;
        const int n  = p0 / HWN, hw0 = p0 % HWN;
        const float* xn = x + (size_t)n * CIN * HWN + hw0;

        // local pairing probe (exact copy of r6-proven probe, LDS result)
        if (t < 64) {
            int l = t;
            union { bf16x8 v; short a[8]; } B;
#pragma unroll
            for (int e = 0; e < 8; ++e) {
                float val = (float)(1u << (((l >> 4) * 8 + e) & 31));
                B.a[e] = (short)f2bf(val);
            }
#pragma unroll
            for (int s = 0; s < 32; ++s) {
                union { bf16x8 v; short a[8]; } A;
#pragma unroll
                for (int e = 0; e < 8; ++e) A.a[e] = 0;
                if ((l >> 4) == (s >> 3)) A.a[s & 7] = (short)f2bf(1.0f);
                f32x4 d = {0.f, 0.f, 0.f, 0.f};
                d = __builtin_amdgcn_mfma_f32_16x16x32_bf16(A.v, B.v, d, 0, 0, 0);
                float v0 = d[0];
                if (l == 0 && v0 > 0.f) {
                    int ex; frexpf(v0, &ex);     // v0 = 2^j -> ex = j+1
                    int j = ex - 1;
                    if (j >= 0 && j < 32) spair[j] = s;
                }
            }
        }
        __syncthreads();
        if (t < CIN) sperm[t] = (t & ~31) | (spair[t & 31] & 31);
        __syncthreads();

        // read: 4 reps x (32 c x 64 px), 32B contiguous per thread
#pragma unroll
        for (int rep = 0; rep < 4; ++rep) {
            const int c  = rep * 32 + (t >> 3);
            const int px = (t & 7) * 8;
            const float* src = xn + (size_t)c * HWN + px;
            float4 a = *(const float4*)src;
            float4 bq = *(const float4*)(src + 4);
            tile[c][px + 0] = a.x;  tile[c][px + 1] = a.y;
            tile[c][px + 2] = a.z;  tile[c][px + 3] = a.w;
            tile[c][px + 4] = bq.x; tile[c][px + 5] = bq.y;
            tile[c][px + 6] = bq.z; tile[c][px + 7] = bq.w;
        }
        __syncthreads();

        // write: chunk c: lane-minor over slot4 -> 2 x 512B contiguous per wave
#pragma unroll
        for (int wc = 0; wc < 8; ++wc) {
            const int idx = wc * 256 + t;       // 0..2047
            const int px  = idx >> 5;           // 0..63
            const int s4  = idx & 31;           // slot quad
            float4 v;
            v.x = tile[sperm[s4 * 4 + 0]][px];
            v.y = tile[sperm[s4 * 4 + 1]][px];
            v.z = tile[sperm[s4 * 4 + 2]][px];
            v.w = tile[sperm[s4 * 4 + 3]][px];
            *(float4*)(xt + ((size_t)(p0 + px)) * CIN + s4 * 4) = v;
        }
        return;
    }

    if (b >= HEADB) {
        // ---------------- wsplit part (r8-proven indexing), hi only
        const int bb = b - HEADB;
        int i = bb * 256 + t;                     // < 147456
        {
            int e  = i & 7;
            int l  = (i >> 3) & 63;
            int ot = (i >> 9) & 7;
            int q  = (i >> 12) & 3;
            int k  = i >> 14;                     // 0..8
            int o  = ot * 16 + (l & 15);
            int c  = q * 32 + (l >> 4) * 8 + e;
            wah[i] = f2bf(wd[o * KDIM + c * KW + k]);
        }
        if (bb == 0 && t < 128) gn_part[t] = 0.f;
        if (bb == 0 && t < 64) {
            // D-layout probe (HW-verified r4/r6)
            int l = t;
            bf16x8 A1 = {}, B1 = {}, A2 = {}, B2 = {};
            if ((l >> 4) == 0) {
                A1[0] = (short)f2bf((float)((l & 15) + 1));
                B1[0] = (short)f2bf(1.0f);
                A2[0] = (short)f2bf(1.0f);
                B2[0] = (short)f2bf((float)((l & 15) + 1));
            }
            f32x4 d1 = {0.f,0.f,0.f,0.f}, d2 = {0.f,0.f,0.f,0.f};
            d1 = __builtin_amdgcn_mfma_f32_16x16x32_bf16(A1, B1, d1, 0, 0, 0);
            d2 = __builtin_amdgcn_mfma_f32_16x16x32_bf16(A2, B2, d2, 0, 0, 0);
#pragma unroll
            for (int r = 0; r < 4; ++r) {
                int m = (int)(d1[r] + 0.5f) - 1;
                int n = (int)(d2[r] + 0.5f) - 1;
                map[l * 4 + r] = (m << 4) | n;
            }
        }
        if (bb == 1 && t < 64) {
            // global pairB probe (kept for ws-layout stability)
            int l = t;
            union { bf16x8 v; short a[8]; } B;
#pragma unroll
            for (int e = 0; e < 8; ++e) {
                float val = (float)(1u << (((l >> 4) * 8 + e) & 31));
                B.a[e] = (short)f2bf(val);
            }
#pragma unroll
            for (int s = 0; s < 32; ++s) {
                union { bf16x8 v; short a[8]; } A;
#pragma unroll
                for (int e = 0; e < 8; ++e) A.a[e] = 0;
                if ((l >> 4) == (s >> 3)) A.a[s & 7] = (short)f2bf(1.0f);
                f32x4 d = {0.f, 0.f, 0.f, 0.f};
                d = __builtin_amdgcn_mfma_f32_16x16x32_bf16(A.v, B.v, d, 0, 0, 0);
                float v0 = d[0];
                if (l == 0 && v0 > 0.f) {
                    int ex; frexpf(v0, &ex);     // v0 = 2^j -> ex = j+1
                    int j = ex - 1;
                    if (j >= 0 && j < 32) pairB[j] = s;
                }
            }
        }
        return;
    }

    // ---------------- head v2 (sliding-window conv)
    float* wl = smem;                                    // CIN*28 = 3584
    float (*sp)[8][13] = (float (*)[8][13])(smem + CIN * 28);   // 32*8*13 = 3328
    for (int i = t; i < 3456; i += 256) {
        int j = i / KDIM, r = i - j * KDIM;
        int c = r / 9, kk = r - c * 9;
        wl[c * 28 + kk * 3 + j] = w_head[i];
    }
    __syncthreads();

    const int sl = t & 7;               // slot in block (4 px each)
    const int cg = t >> 3;              // 0..31, 4 channels each
    const int p0 = b * 32 + sl * 4;     // first pixel of slot
    const int n  = p0 / HWN;
    const int hw = p0 - n * HWN;
    const int h  = hw / WW;
    const int w0 = hw - h * WW;         // multiple of 4 -> float4-aligned
    const float* xn = x + (size_t)n * CIN * HWN;
    const bool lok = (w0 > 0);
    const bool rok = (w0 < WW - 4);

    float acc[12];
#pragma unroll
    for (int i = 0; i < 12; ++i) acc[i] = 0.f;

#pragma unroll
    for (int cc = 0; cc < 4; ++cc) {
        const int c = cg * 4 + cc;
        const float* xc = xn + (size_t)c * HWN;
        float v[3][6];
#pragma unroll
        for (int r = 0; r < 3; ++r) {
            int y = h - 1 + r;
            if (y >= 0 && y < HH) {
                const float* xr = xc + y * WW + w0;
                float4 m4 = *(const float4*)xr;
                v[r][1] = m4.x; v[r][2] = m4.y; v[r][3] = m4.z; v[r][4] = m4.w;
                v[r][0] = lok ? xr[-1] : 0.f;
                v[r][5] = rok ? xr[4]  : 0.f;
            } else {
#pragma unroll
                for (int i = 0; i < 6; ++i) v[r][i] = 0.f;
            }
        }
        float wr[28];
        const float* wc = &wl[c * 28];
#pragma unroll
        for (int i2 = 0; i2 < 7; ++i2) {
            float4 q4 = *(const float4*)(wc + i2 * 4);
            wr[i2 * 4 + 0] = q4.x; wr[i2 * 4 + 1] = q4.y;
            wr[i2 * 4 + 2] = q4.z; wr[i2 * 4 + 3] = q4.w;
        }
#pragma unroll
        for (int ky = 0; ky < 3; ++ky)
#pragma unroll
            for (int kx = 0; kx < 3; ++kx) {
                const int kk = ky * 3 + kx;
                const float wj0 = wr[kk * 3 + 0];
                const float wj1 = wr[kk * 3 + 1];
                const float wj2 = wr[kk * 3 + 2];
#pragma unroll
                for (int q = 0; q < 4; ++q) {
                    float val = v[ky][q + kx];
                    acc[q * 3 + 0] = fmaf(val, wj0, acc[q * 3 + 0]);
                    acc[q * 3 + 1] = fmaf(val, wj1, acc[q * 3 + 1]);
                    acc[q * 3 + 2] = fmaf(val, wj2, acc[q * 3 + 2]);
                }
            }
    }
#pragma unroll
    for (int i = 0; i < 12; ++i) sp[cg][sl][i] = acc[i];
    __syncthreads();
    if (cg < 8) {
#pragma unroll
        for (int k = 8; k < 32; k += 8)
#pragma unroll
            for (int i = 0; i < 12; ++i) sp[cg][sl][i] += sp[cg + k][sl][i];
    }
    __syncthreads();
    if (t < 32) {
        const int s2 = t >> 2, q = t & 3;
        float b0 = b_head[0], b1 = b_head[1], b2 = b_head[2];
#pragma unroll
        for (int cgi = 0; cgi < 8; ++cgi) {
            b0 += sp[cgi][s2][q * 3 + 0];
            b1 += sp[cgi][s2][q * 3 + 1];
            b2 += sp[cgi][s2][q * 3 + 2];
        }
        int pp = b * 32 + t;
        dxv[pp]   = 0.25f * tanhf(b0);
        dyv[pp]   = 0.25f * tanhf(b1);
        maskv[pp] = 1.f / (1.f + expf(-b2));
    }
}

// ---------------------------------------------------------------- main DCN
// r11 pipeline skeleton + xt gathers + lane remap (r3-proven). This round:
// DISTANCE-2 software pipeline — gathers for phase j+2 issued during phase j,
// two raw/A-frag/corner register sets, so ~2 phases of work cover the
// L2/L3 gather latency instead of <1.
__global__ __launch_bounds__(256, 3) void dcn_kernel(const float* __restrict__ xt,
                                                  const ushort* __restrict__ wah,
                                                  const float* __restrict__ dxv,
                                                  const float* __restrict__ dyv,
                                                  const float* __restrict__ maskv,
                                                  const int* __restrict__ map,
                                                  float* __restrict__ out,
                                                  float* __restrict__ gn_part) {
    __shared__ __attribute__((aligned(16))) ushort sBh[2][4 * PXB * 8];  // 4 KB
    __shared__ float sMask[PXB];
    __shared__ float gred[16];

    const int t = threadIdx.x;
    const int lane = t & 63;
    const int wv = t >> 6;
    const int lg = lane >> 4;
    const int ml = lane & 15;
    const int pix = t >> 3;         // 0..31 (8 adjacent lanes share a pixel)
    const int sg  = t & 7;          // slot quad sg*4..sg*4+3

    int b = blockIdx.x;
    int nb = (b & 7) * (NBLK / 8) + (b >> 3);     // XCD swizzle
    const int p0  = nb * PXB;
    const int n   = p0 / HWN;
    const int hw0 = p0 % HWN;
    const float* xtn = xt + (size_t)n * HWN * CIN;

    if (t < PXB) sMask[t] = maskv[p0 + t];
    if (t < 16) gred[t] = 0.f;

    const float dxl = dxv[p0 + pix];
    const float dyl = dyv[p0 + pix];
    const int hme = (hw0 + pix) / WW;
    const int wme = (hw0 + pix) % WW;

    f32x4 acc[2][2];
#pragma unroll
    for (int i = 0; i < 2; i++)
#pragma unroll
        for (int j = 0; j < 2; j++) acc[i][j] = (f32x4){0.f, 0.f, 0.f, 0.f};

    const int oyc[9] = {0, 0, 0, 1, 0, -1, 1, 1, -1};
    const int oxc[9] = {0, 1, -1, 0, 0, 0, 1, -1, 1};
    const int ncl[9] = {1, 2, 2, 2, 1, 2, 4, 4, 4};

    // distance-2 pipeline state: [set] indexed by compile-time constants only
    int    aa[2][4];      // corner sets, by tap parity
    float  wq[2][4];
    float4 vr[2][4];      // raw gathers, by phase parity
    bf16x8 An[2][2];      // A frags, by phase parity

#define CORNERS(kn_, cs_) {                                                    \
    const int ky = (kn_) / 3, kx = (kn_) - ky * 3;                             \
    float py = (float)(hme - 1 + ky) + (float)oyc[kn_] * dxl;                  \
    float px = (float)(wme - 1 + kx) + (float)oxc[kn_] * dyl;                  \
    float fy0 = floorf(py), fx0 = floorf(px);                                  \
    int y0 = (int)fy0, x0 = (int)fx0;                                          \
    float fy = py - fy0, fx = px - fx0;                                        \
    _Pragma("unroll")                                                          \
    for (int jj = 0; jj < 4; ++jj) {                                           \
        int yy = y0 + (jj >> 1), xx = x0 + (jj & 1);                           \
        float wb = ((jj >> 1) ? fy : 1.f - fy) * ((jj & 1) ? fx : 1.f - fx);   \
        bool ok = (yy >= 0) && (yy < HH) && (xx >= 0) && (xx < WW);            \
        aa[cs_][jj] = min(max(yy, 0), HH - 1) * WW + min(max(xx, 0), WW - 1);  \
        wq[cs_][jj] = ok ? wb : 0.f;                                           \
    }                                                                          \
    if (ncl[kn_] == 2 && oxc[kn_] == 0) {                                      \
        aa[cs_][1] = aa[cs_][2]; wq[cs_][1] = wq[cs_][2];                      \
    } }

#define ISSUE(jn_, rs_, cs_) {                                                 \
    const int qn_ = (jn_) & 3, NCn_ = ncl[(jn_) >> 2];                         \
    const int co_ = qn_ * 32 + sg * 4;                                         \
    vr[rs_][0] = *(const float4*)(xtn + ((aa[cs_][0] << 7) + co_));            \
    if (NCn_ >= 2) vr[rs_][1] = *(const float4*)(xtn + ((aa[cs_][1] << 7) + co_)); \
    if (NCn_ == 4) {                                                           \
        vr[rs_][2] = *(const float4*)(xtn + ((aa[cs_][2] << 7) + co_));        \
        vr[rs_][3] = *(const float4*)(xtn + ((aa[cs_][3] << 7) + co_));        \
    }                                                                          \
    const size_t abase_ = (size_t)((jn_) * 8 + wv * 2) * 512 + lane * 8;       \
    An[rs_][0] = *(const bf16x8*)(wah + abase_);                               \
    An[rs_][1] = *(const bf16x8*)(wah + abase_ + 512);                         \
    }

    // ---- prologue: tap0 corners, issue phases 0 and 1 (tap0 q0, q1)
    CORNERS(0, 0);
    ISSUE(0, 0, 0);
    ISSUE(1, 1, 0);

#pragma unroll
    for (int j = 0; j < 36; ++j) {
        const int k  = j >> 2;
        const int NC = ncl[k];
        const int cs = k & 1;
        const int rs = j & 1;
        bf16x8 Ah0 = An[rs][0], Ah1 = An[rs][1];
        // ---- pack set j (waits on j's gathers — issued two phases ago)
        union { short4 v; ushort u[4]; } hv;
        {
            float s0 = vr[rs][0].x * wq[cs][0], s1 = vr[rs][0].y * wq[cs][0];
            float s2 = vr[rs][0].z * wq[cs][0], s3 = vr[rs][0].w * wq[cs][0];
            if (NC >= 2) {
                s0 = fmaf(vr[rs][1].x, wq[cs][1], s0); s1 = fmaf(vr[rs][1].y, wq[cs][1], s1);
                s2 = fmaf(vr[rs][1].z, wq[cs][1], s2); s3 = fmaf(vr[rs][1].w, wq[cs][1], s3);
            }
            if (NC == 4) {
                s0 = fmaf(vr[rs][2].x, wq[cs][2], s0); s1 = fmaf(vr[rs][2].y, wq[cs][2], s1);
                s2 = fmaf(vr[rs][2].z, wq[cs][2], s2); s3 = fmaf(vr[rs][2].w, wq[cs][2], s3);
                s0 = fmaf(vr[rs][3].x, wq[cs][3], s0); s1 = fmaf(vr[rs][3].y, wq[cs][3], s1);
                s2 = fmaf(vr[rs][3].z, wq[cs][3], s2); s3 = fmaf(vr[rs][3].w, wq[cs][3], s3);
            }
            hv.u[0] = f2bf(s0); hv.u[1] = f2bf(s1);
            hv.u[2] = f2bf(s2); hv.u[3] = f2bf(s3);
        }
        const int wbase = ((sg >> 1) * PXB + pix) * 8 + (sg & 1) * 4;
        *(short4*)&sBh[rs][wbase] = hv.v;
        // ---- issue phase j+2 (raw set rs is free now; corner set by tap parity)
        if (j < 34) {
            const int jn = j + 2, kn = jn >> 2, qn = jn & 3, csn = kn & 1;
            if (qn == 0) CORNERS(kn, csn);
            ISSUE(jn, rs, csn);
        }
        barrier_keep_vm();   // drains LDS writes; gathers stay outstanding
        // ---- MFMAs on buf[rs]
#pragma unroll
        for (int pt = 0; pt < 2; ++pt) {
            const int rbase = (lg * PXB + pt * 16 + ml) * 8;
            bf16x8 Bh = *(const bf16x8*)&sBh[rs][rbase];
            acc[0][pt] = __builtin_amdgcn_mfma_f32_16x16x32_bf16(Ah0, Bh, acc[0][pt], 0, 0, 0);
            acc[1][pt] = __builtin_amdgcn_mfma_f32_16x16x32_bf16(Ah1, Bh, acc[1][pt], 0, 0, 0);
        }
    }
#undef CORNERS
#undef ISSUE

    // ---- epilogue: mask, scatter via probed D layout, GN partials (r8-proven)
    int4 mn4 = *(const int4*)&map[lane * 4];
    int mn[4] = {mn4.x, mn4.y, mn4.z, mn4.w};
    float s1g[2] = {0.f, 0.f}, s2g[2] = {0.f, 0.f};
#pragma unroll
    for (int ot = 0; ot < 2; ++ot) {
        int otile = wv * 32 + ot * 16;
#pragma unroll
        for (int pt = 0; pt < 2; ++pt) {
#pragma unroll
            for (int r = 0; r < 4; ++r) {
                int m = mn[r] >> 4, nn2 = mn[r] & 15;
                int p = pt * 16 + nn2;
                float v = acc[ot][pt][r] * sMask[p];
                s1g[ot] += v;
                s2g[ot] += v * v;
                out[((size_t)n * COUT + otile + m) * HWN + hw0 + p] = v;
            }
        }
    }
#pragma unroll
    for (int ot = 0; ot < 2; ++ot) {
        int g = wv * 2 + ot;
        atomicAdd(&gred[g * 2 + 0], s1g[ot]);
        atomicAdd(&gred[g * 2 + 1], s2g[ot]);
    }
    __syncthreads();
    if (t < 8) {
        atomicAdd(&gn_part[n * 8 + t],      gred[t * 2 + 0]);
        atomicAdd(&gn_part[64 + n * 8 + t], gred[t * 2 + 1]);
    }
}

// ---------------------------------------------------------------- GN apply (stats inline)
__global__ __launch_bounds__(256) void gn_apply(float* __restrict__ out,
                                                const float* __restrict__ gn_part,
                                                const float* __restrict__ gamma,
                                                const float* __restrict__ beta) {
    int i4 = blockIdx.x * 256 + threadIdx.x;
    size_t e = (size_t)i4 * 4;
    int og = (int)(e / HWN);
    int n = og >> 7, o = og & 127;
    int s = n * 8 + (o >> 4);
    const float cnt = (float)GSZ * (float)HWN;
    float s1 = gn_part[s], s2 = gn_part[64 + s];
    float mu = s1 / cnt;
    float var = s2 / cnt - mu * mu;
    float inv = rsqrtf(var + 1e-5f);
    float ga = gamma[o] * inv;
    float be = beta[o] - mu * ga;
    float4 v = *(float4*)(out + e);
    v.x = fmaxf(fmaf(v.x, ga, be), 0.f);
    v.y = fmaxf(fmaf(v.y, ga, be), 0.f);
    v.z = fmaxf(fmaf(v.z, ga, be), 0.f);
    v.w = fmaxf(fmaf(v.w, ga, be), 0.f);
    *(float4*)(out + e) = v;
}

// ---------------------------------------------------------------- launch
extern "C" void kernel_launch(void* const* d_in, const int* in_sizes, int n_in,
                              void* d_out, int out_size, void* d_ws, size_t ws_size,
                              hipStream_t stream) {
    const float* x       = (const float*)d_in[0];
    const float* w_head  = (const float*)d_in[1];
    const float* b_head  = (const float*)d_in[2];
    const float* w_dcn   = (const float*)d_in[3];
    const float* gamma   = (const float*)d_in[4];
    const float* beta    = (const float*)d_in[5];
    float* out = (float*)d_out;
    float* ws  = (float*)d_ws;

    ushort* wah    = (ushort*)(ws + OFF_WAH);
    float* dxv     = ws + OFF_DX;
    float* dyv     = ws + OFF_DY;
    float* maskv   = ws + OFF_MASK;
    float* gn_part = ws + OFF_GN;
    int*   map     = (int*)(ws + OFF_MAP);
    int*   pairB   = (int*)(ws + OFF_PAIR);
    float* xt      = ws + OFF_XT;

    pre_kernel<<<HEADB + 576 + XPOB, 256, 0, stream>>>(x, w_head, b_head, w_dcn, wah,
                                                       dxv, dyv, maskv, gn_part, map, pairB, xt);
    dcn_kernel<<<NBLK, 256, 0, stream>>>(xt, wah, dxv, dyv, maskv, map, out, gn_part);
    gn_apply<<<(NB * COUT * HWN) / 4 / 256, 256, 0, stream>>>(out, gn_part, gamma, beta);
}